// Round 1
// baseline (481.413 us; speedup 1.0000x reference)
//
#include <hip/hip_runtime.h>
#include <hip/hip_bf16.h>

#define BB 4
#define SS 2048
#define HH 576
#define NHD 9
#define NKVH 3
#define HDIM 64

using s8v = __attribute__((ext_vector_type(8))) short;
using f4v = __attribute__((ext_vector_type(4))) float;

__device__ __forceinline__ unsigned short f2bf(float f) {
  union { float f; unsigned u; } x; x.f = f;
  unsigned r = x.u + 0x7fffu + ((x.u >> 16) & 1u);
  return (unsigned short)(r >> 16);
}

// ---------------- kernel 1: cast hidden_states fp32 -> bf16 ----------------
__global__ void cast_x_kernel(const float* __restrict__ hs, unsigned short* __restrict__ xb) {
  long i = (long)blockIdx.x * blockDim.x + threadIdx.x;
  long base = i * 4;  // total elements 8192*576, divisible by 4*256
  float4 v = *(const float4*)(hs + base);
  ushort4 o;
  o.x = f2bf(v.x); o.y = f2bf(v.y); o.z = f2bf(v.z); o.w = f2bf(v.w);
  *(ushort4*)(xb + base) = o;
}

// ------------- kernel 2: pack weights -> bf16, transposed [n][k] -----------
__global__ void pack_w_kernel(const float* __restrict__ wq, const float* __restrict__ wk,
                              const float* __restrict__ wv, const float* __restrict__ wo,
                              unsigned short* __restrict__ wqkvt, unsigned short* __restrict__ wot) {
  int i = blockIdx.x * blockDim.x + threadIdx.x;
  if (i < 960 * 576) {
    int n = i / 576, k = i % 576;
    float val;
    if (n < 576)      val = wq[k * 576 + n];
    else if (n < 768) val = wk[k * 192 + (n - 576)];
    else              val = wv[k * 192 + (n - 768)];
    wqkvt[n * 576 + k] = f2bf(val);
  } else {
    int j = i - 960 * 576;   // total grid sized exactly: j < 576*576
    int n = j / 576, k = j % 576;
    wot[n * 576 + k] = f2bf(wo[k * 576 + n]);
  }
}

// ---- kernel 3: QKV GEMM (bf16 MFMA) + fused RoPE; writes Q,K,[Vt] bf16 ----
// Each wave: 16 rows x 64 cols (one head-chunk). grid = (8192/64, 15), block 256.
__global__ __launch_bounds__(256) void qkv_gemm_kernel(
    const unsigned short* __restrict__ xb, const unsigned short* __restrict__ wt,
    const float* __restrict__ rot,
    unsigned short* __restrict__ qbuf, unsigned short* __restrict__ kbuf,
    unsigned short* __restrict__ vtbuf)
{
  const int lane = threadIdx.x & 63;
  const int wid  = threadIdx.x >> 6;
  const int l15 = lane & 15, hi = lane >> 4;
  const int m0 = blockIdx.x * 64 + wid * 16;
  const int g  = blockIdx.y;          // 0..8 Q heads, 9..11 K heads, 12..14 V heads
  const int n0 = g * 64;

  const f4v zero = {0.f, 0.f, 0.f, 0.f};
  f4v acc[4] = {zero, zero, zero, zero};

  for (int kk = 0; kk < 18; ++kk) {
    const int k0 = kk * 32 + hi * 8;
    s8v a = *(const s8v*)(xb + (long)(m0 + l15) * 576 + k0);
#pragma unroll
    for (int nb = 0; nb < 4; ++nb) {
      s8v b = *(const s8v*)(wt + (long)(n0 + nb * 16 + l15) * 576 + k0);
      acc[nb] = __builtin_amdgcn_mfma_f32_16x16x32_bf16(a, b, acc[nb], 0, 0, 0);
    }
  }

  const int row_base = m0 + hi * 4;
  if (g < 12) {  // RoPE for Q and K heads (pairs d <-> d+32 are nb <-> nb+2, same lane)
#pragma unroll
    for (int r = 0; r < 4; ++r) {
      const int s = (row_base + r) & (SS - 1);
#pragma unroll
      for (int nb = 0; nb < 2; ++nb) {
        const int d = l15 + nb * 16;              // d in [0,32)
        const float sn = rot[s * 64 + d];
        const float cs = rot[s * 64 + 32 + d];
        const float x1 = acc[nb][r], x2 = acc[nb + 2][r];
        acc[nb][r]     = x1 * cs - x2 * sn;
        acc[nb + 2][r] = x1 * sn + x2 * cs;
      }
    }
  }

  if (g < 9) {            // Q head
    const int h = g;
#pragma unroll
    for (int r = 0; r < 4; ++r) {
      const int row = row_base + r, b = row >> 11, s = row & (SS - 1);
      unsigned short* dst = qbuf + ((long)((b * NHD + h) * SS + s)) * HDIM;
#pragma unroll
      for (int nb = 0; nb < 4; ++nb) dst[l15 + nb * 16] = f2bf(acc[nb][r]);
    }
  } else if (g < 12) {    // K head
    const int h = g - 9;
#pragma unroll
    for (int r = 0; r < 4; ++r) {
      const int row = row_base + r, b = row >> 11, s = row & (SS - 1);
      unsigned short* dst = kbuf + ((long)((b * NKVH + h) * SS + s)) * HDIM;
#pragma unroll
      for (int nb = 0; nb < 4; ++nb) dst[l15 + nb * 16] = f2bf(acc[nb][r]);
    }
  } else {                // V head -> transposed [b][h][d][s]
    const int h = g - 12;
#pragma unroll
    for (int r = 0; r < 4; ++r) {
      const int row = row_base + r, b = row >> 11, s = row & (SS - 1);
#pragma unroll
      for (int nb = 0; nb < 4; ++nb) {
        const int d = l15 + nb * 16;
        vtbuf[((long)((b * NKVH + h) * HDIM + d)) * SS + s] = f2bf(acc[nb][r]);
      }
    }
  }
}

// -------- kernel 4: flash attention. 1 wave = 16 Q-rows, KV tile = 32 -------
// grid = (2048/64, 36), block 256 (4 independent waves; wave-local LDS only).
__global__ __launch_bounds__(256) void flash_kernel(
    const unsigned short* __restrict__ qbuf, const unsigned short* __restrict__ kbuf,
    const unsigned short* __restrict__ vtbuf, unsigned short* __restrict__ obuf)
{
  __shared__ float plds[4][16][33];
  const int lane = threadIdx.x & 63, wid = threadIdx.x >> 6;
  const int l15 = lane & 15, hi = lane >> 4;
  const int bh = blockIdx.y;
  const int b = bh / NHD, h = bh % NHD;
  const int hkv = h / 3;
  const int q0 = blockIdx.x * 64 + wid * 16;

  const unsigned short* Q  = qbuf + ((long)(b * NHD + h) * SS) * HDIM;
  const unsigned short* K  = kbuf + ((long)(b * NKVH + hkv) * SS) * HDIM;
  const unsigned short* Vt = vtbuf + ((long)(b * NKVH + hkv) * HDIM) * SS;

  const s8v qa0 = *(const s8v*)(Q + (long)(q0 + l15) * HDIM + hi * 8);
  const s8v qa1 = *(const s8v*)(Q + (long)(q0 + l15) * HDIM + 32 + hi * 8);

  const f4v zero = {0.f, 0.f, 0.f, 0.f};
  f4v accO[4] = {zero, zero, zero, zero};
  float m_run[4] = {-1e30f, -1e30f, -1e30f, -1e30f};
  float l_run[4] = {0.f, 0.f, 0.f, 0.f};

  const int kv_end = q0 + 16;  // causal: last kv needed is q0+15
  for (int kv0 = 0; kv0 < kv_end; kv0 += 32) {
    const s8v kb00 = *(const s8v*)(K + (long)(kv0 + l15) * HDIM + hi * 8);
    const s8v kb01 = *(const s8v*)(K + (long)(kv0 + l15) * HDIM + 32 + hi * 8);
    const s8v kb10 = *(const s8v*)(K + (long)(kv0 + 16 + l15) * HDIM + hi * 8);
    const s8v kb11 = *(const s8v*)(K + (long)(kv0 + 16 + l15) * HDIM + 32 + hi * 8);
    f4v s0 = __builtin_amdgcn_mfma_f32_16x16x32_bf16(qa0, kb00, zero, 0, 0, 0);
    s0     = __builtin_amdgcn_mfma_f32_16x16x32_bf16(qa1, kb01, s0,   0, 0, 0);
    f4v s1 = __builtin_amdgcn_mfma_f32_16x16x32_bf16(qa0, kb10, zero, 0, 0, 0);
    s1     = __builtin_amdgcn_mfma_f32_16x16x32_bf16(qa1, kb11, s1,   0, 0, 0);

    const int kvc0 = kv0 + l15, kvc1 = kv0 + 16 + l15;
#pragma unroll
    for (int r = 0; r < 4; ++r) {
      const int q = q0 + hi * 4 + r;
      float a0 = s0[r] * 0.125f + (kvc0 <= q ? 0.f : -1e9f);
      float a1 = s1[r] * 0.125f + (kvc1 <= q ? 0.f : -1e9f);
      float t = fmaxf(a0, a1);
      t = fmaxf(t, __shfl_xor(t, 1));
      t = fmaxf(t, __shfl_xor(t, 2));
      t = fmaxf(t, __shfl_xor(t, 4));
      t = fmaxf(t, __shfl_xor(t, 8));
      const float nm = fmaxf(m_run[r], t);
      const float corr = __expf(m_run[r] - nm);
      m_run[r] = nm;
      const float p0 = __expf(a0 - nm);
      const float p1 = __expf(a1 - nm);
      float rs = p0 + p1;
      rs += __shfl_xor(rs, 1);
      rs += __shfl_xor(rs, 2);
      rs += __shfl_xor(rs, 4);
      rs += __shfl_xor(rs, 8);
      l_run[r] = l_run[r] * corr + rs;
#pragma unroll
      for (int nb = 0; nb < 4; ++nb) accO[nb][r] *= corr;
      plds[wid][hi * 4 + r][l15] = p0;
      plds[wid][hi * 4 + r][16 + l15] = p1;
    }
    // transpose P through wave-local LDS -> A-fragment (row=l15, k=hi*8+j)
    s8v pa;
#pragma unroll
    for (int j = 0; j < 8; ++j) pa[j] = (short)f2bf(plds[wid][l15][hi * 8 + j]);
#pragma unroll
    for (int nb = 0; nb < 4; ++nb) {
      s8v vb = *(const s8v*)(Vt + (long)(nb * 16 + l15) * SS + kv0 + hi * 8);
      accO[nb] = __builtin_amdgcn_mfma_f32_16x16x32_bf16(pa, vb, accO[nb], 0, 0, 0);
    }
  }

#pragma unroll
  for (int r = 0; r < 4; ++r) {
    const float inv = 1.f / l_run[r];
    const int s = q0 + hi * 4 + r;
#pragma unroll
    for (int nb = 0; nb < 4; ++nb) {
      obuf[(long)(b * SS + s) * HH + h * HDIM + nb * 16 + l15] = f2bf(accO[nb][r] * inv);
    }
  }
}

// ----------------- kernel 5: output projection -> fp32 d_out ----------------
__global__ __launch_bounds__(256) void out_gemm_kernel(
    const unsigned short* __restrict__ ob, const unsigned short* __restrict__ wot,
    float* __restrict__ out)
{
  const int lane = threadIdx.x & 63;
  const int wid  = threadIdx.x >> 6;
  const int l15 = lane & 15, hi = lane >> 4;
  const int m0 = blockIdx.x * 64 + wid * 16;
  const int n0 = blockIdx.y * 64;

  const f4v zero = {0.f, 0.f, 0.f, 0.f};
  f4v acc[4] = {zero, zero, zero, zero};

  for (int kk = 0; kk < 18; ++kk) {
    const int k0 = kk * 32 + hi * 8;
    s8v a = *(const s8v*)(ob + (long)(m0 + l15) * 576 + k0);
#pragma unroll
    for (int nb = 0; nb < 4; ++nb) {
      s8v b = *(const s8v*)(wot + (long)(n0 + nb * 16 + l15) * 576 + k0);
      acc[nb] = __builtin_amdgcn_mfma_f32_16x16x32_bf16(a, b, acc[nb], 0, 0, 0);
    }
  }
#pragma unroll
  for (int r = 0; r < 4; ++r) {
    const int row = m0 + hi * 4 + r;
#pragma unroll
    for (int nb = 0; nb < 4; ++nb) {
      out[(long)row * 576 + n0 + nb * 16 + l15] = acc[nb][r];
    }
  }
}

extern "C" void kernel_launch(void* const* d_in, const int* in_sizes, int n_in,
                              void* d_out, int out_size, void* d_ws, size_t ws_size,
                              hipStream_t stream) {
  const float* hs  = (const float*)d_in[0];
  // d_in[1] = attention_mask (pure causal -1e9 mask) — applied analytically.
  const float* rot = (const float*)d_in[2];
  const float* wq  = (const float*)d_in[3];
  const float* wk  = (const float*)d_in[4];
  const float* wv  = (const float*)d_in[5];
  const float* wo  = (const float*)d_in[6];
  float* out = (float*)d_out;

  char* ws = (char*)d_ws;
  // workspace layout (bytes)
  unsigned short* xb    = (unsigned short*)(ws + 0);          // 8192x576 bf16   = 9,437,184
  unsigned short* wqkvt = (unsigned short*)(ws + 9437184);    // 960x576 bf16    = 1,105,920
  unsigned short* wot   = (unsigned short*)(ws + 10543104);   // 576x576 bf16    =   663,552
  unsigned short* qb    = (unsigned short*)(ws + 11206656);   // 4x9x2048x64     = 9,437,184
  unsigned short* kb    = (unsigned short*)(ws + 20643840);   // 4x3x2048x64     = 3,145,728
  unsigned short* vt    = (unsigned short*)(ws + 23789568);   // 4x3x64x2048     = 3,145,728
  unsigned short* obuf  = (unsigned short*)(ws + 26935296);   // 8192x576 bf16   = 9,437,184
  // total 36,372,480 bytes

  cast_x_kernel<<<4608, 256, 0, stream>>>(hs, xb);
  pack_w_kernel<<<3456, 256, 0, stream>>>(wq, wk, wv, wo, wqkvt, wot);
  qkv_gemm_kernel<<<dim3(128, 15), 256, 0, stream>>>(xb, wqkvt, rot, qb, kb, vt);
  flash_kernel<<<dim3(32, 36), 256, 0, stream>>>(qb, kb, vt, obuf);
  out_gemm_kernel<<<dim3(128, 9), 256, 0, stream>>>(obuf, wot, out);
}

// Round 2
// 303.305 us; speedup vs baseline: 1.5872x; 1.5872x over previous
//
#include <hip/hip_runtime.h>
#include <hip/hip_bf16.h>

#define BB 4
#define SS 2048
#define HH 576
#define NHD 9
#define NKVH 3
#define HDIM 64

using s8v = __attribute__((ext_vector_type(8))) short;
using f4v = __attribute__((ext_vector_type(4))) float;

__device__ __forceinline__ unsigned short f2bf(float f) {
  union { float f; unsigned u; } x; x.f = f;
  unsigned r = x.u + 0x7fffu + ((x.u >> 16) & 1u);
  return (unsigned short)(r >> 16);
}

__device__ __forceinline__ unsigned pk2bf(float lo, float hi) {
  union { __hip_bfloat162 h; unsigned u; } c;
  c.h = __float22bfloat162_rn(make_float2(lo, hi));
  return c.u;
}

// ---------------- kernel 1: cast hidden_states fp32 -> bf16 ----------------
__global__ void cast_x_kernel(const float* __restrict__ hs, unsigned short* __restrict__ xb) {
  long i = (long)blockIdx.x * blockDim.x + threadIdx.x;
  long base = i * 4;
  float4 v = *(const float4*)(hs + base);
  ushort4 o;
  o.x = f2bf(v.x); o.y = f2bf(v.y); o.z = f2bf(v.z); o.w = f2bf(v.w);
  *(ushort4*)(xb + base) = o;
}

// ------------- kernel 2: pack weights -> bf16, transposed [n][k] -----------
__global__ void pack_w_kernel(const float* __restrict__ wq, const float* __restrict__ wk,
                              const float* __restrict__ wv, const float* __restrict__ wo,
                              unsigned short* __restrict__ wqkvt, unsigned short* __restrict__ wot) {
  int i = blockIdx.x * blockDim.x + threadIdx.x;
  if (i < 960 * 576) {
    int n = i / 576, k = i % 576;
    float val;
    if (n < 576)      val = wq[k * 576 + n];
    else if (n < 768) val = wk[k * 192 + (n - 576)];
    else              val = wv[k * 192 + (n - 768)];
    wqkvt[n * 576 + k] = f2bf(val);
  } else {
    int j = i - 960 * 576;
    int n = j / 576, k = j % 576;
    wot[n * 576 + k] = f2bf(wo[k * 576 + n]);
  }
}

// ---- kernel 3: QKV GEMM (bf16 MFMA) + fused RoPE; writes Q,K,[Vt] bf16 ----
// Q is pre-scaled by 1/sqrt(HD)=0.125 (exact pow2 in bf16).
__global__ __launch_bounds__(256) void qkv_gemm_kernel(
    const unsigned short* __restrict__ xb, const unsigned short* __restrict__ wt,
    const float* __restrict__ rot,
    unsigned short* __restrict__ qbuf, unsigned short* __restrict__ kbuf,
    unsigned short* __restrict__ vtbuf)
{
  const int lane = threadIdx.x & 63;
  const int wid  = threadIdx.x >> 6;
  const int l15 = lane & 15, hi = lane >> 4;
  const int m0 = blockIdx.x * 64 + wid * 16;
  const int g  = blockIdx.y;
  const int n0 = g * 64;

  const f4v zero = {0.f, 0.f, 0.f, 0.f};
  f4v acc[4] = {zero, zero, zero, zero};

  for (int kk = 0; kk < 18; ++kk) {
    const int k0 = kk * 32 + hi * 8;
    s8v a = *(const s8v*)(xb + (long)(m0 + l15) * 576 + k0);
#pragma unroll
    for (int nb = 0; nb < 4; ++nb) {
      s8v b = *(const s8v*)(wt + (long)(n0 + nb * 16 + l15) * 576 + k0);
      acc[nb] = __builtin_amdgcn_mfma_f32_16x16x32_bf16(a, b, acc[nb], 0, 0, 0);
    }
  }

  const int row_base = m0 + hi * 4;
  if (g < 12) {  // RoPE (pairs d <-> d+32 live in nb <-> nb+2, same lane)
#pragma unroll
    for (int r = 0; r < 4; ++r) {
      const int s = (row_base + r) & (SS - 1);
#pragma unroll
      for (int nb = 0; nb < 2; ++nb) {
        const int d = l15 + nb * 16;
        const float sn = rot[s * 64 + d];
        const float cs = rot[s * 64 + 32 + d];
        const float x1 = acc[nb][r], x2 = acc[nb + 2][r];
        acc[nb][r]     = x1 * cs - x2 * sn;
        acc[nb + 2][r] = x1 * sn + x2 * cs;
      }
    }
  }

  if (g < 9) {            // Q head (scaled by 0.125)
    const int h = g;
#pragma unroll
    for (int r = 0; r < 4; ++r) {
      const int row = row_base + r, b = row >> 11, s = row & (SS - 1);
      unsigned short* dst = qbuf + ((long)((b * NHD + h) * SS + s)) * HDIM;
#pragma unroll
      for (int nb = 0; nb < 4; ++nb) dst[l15 + nb * 16] = f2bf(acc[nb][r] * 0.125f);
    }
  } else if (g < 12) {    // K head
    const int h = g - 9;
#pragma unroll
    for (int r = 0; r < 4; ++r) {
      const int row = row_base + r, b = row >> 11, s = row & (SS - 1);
      unsigned short* dst = kbuf + ((long)((b * NKVH + h) * SS + s)) * HDIM;
#pragma unroll
      for (int nb = 0; nb < 4; ++nb) dst[l15 + nb * 16] = f2bf(acc[nb][r]);
    }
  } else {                // V head -> transposed [b][h][d][s]
    const int h = g - 12;
#pragma unroll
    for (int r = 0; r < 4; ++r) {
      const int row = row_base + r, b = row >> 11, s = row & (SS - 1);
#pragma unroll
      for (int nb = 0; nb < 4; ++nb) {
        const int d = l15 + nb * 16;
        vtbuf[((long)((b * NKVH + h) * HDIM + d)) * SS + s] = f2bf(acc[nb][r]);
      }
    }
  }
}

// -------- kernel 4: flash attention, swapped QK^T (lane-local softmax) -----
// 1 wave = 16 q rows (q = q0 + l15 via B-fragment cols). KV tile = 32.
// No LDS. Row-reduce: 7 in-lane fmax + 2 shfl_xor. P redistribution: 8
// independent shfls. K-tile prefetch. Boundary-only causal mask.
// grid: 2304 blocks x 128 threads (2 waves), descending-work order.
__global__ __launch_bounds__(128, 4) void flash_kernel(
    const unsigned short* __restrict__ qbuf, const unsigned short* __restrict__ kbuf,
    const unsigned short* __restrict__ vtbuf, unsigned short* __restrict__ obuf)
{
  const int lane = threadIdx.x & 63, wid = threadIdx.x >> 6;
  const int l15 = lane & 15, hi = lane >> 4;
  const int widx = blockIdx.x * 2 + wid;          // 0..4607
  const int qs = 127 - widx / 36;                 // descending work
  const int bh = widx % 36;
  const int q0 = qs * 16;
  const int b = bh / NHD, h = bh % NHD;
  const int hkv = h / 3;

  const unsigned short* Q  = qbuf + ((long)(b * NHD + h) * SS) * HDIM;
  const unsigned short* K  = kbuf + ((long)(b * NKVH + hkv) * SS) * HDIM;
  const unsigned short* Vt = vtbuf + ((long)(b * NKVH + hkv) * HDIM) * SS;

  // Q as B-fragment: col q = q0+l15, k = hi*8+j
  const s8v qb0 = *(const s8v*)(Q + (long)(q0 + l15) * HDIM + hi * 8);
  const s8v qb1 = *(const s8v*)(Q + (long)(q0 + l15) * HDIM + 32 + hi * 8);

  const f4v zero = {0.f, 0.f, 0.f, 0.f};
  f4v accO[4] = {zero, zero, zero, zero};
  float m_run = -1e30f, l_run = 0.f;

  const int srcA = l15 + ((hi & 1) << 5);   // lane with hi = (hi&1)*2
  const int srcB = srcA + 16;
  const bool hih = hi >= 2;

  // preload K-fragments for tile 0 (rows kv = l15 / 16+l15)
  s8v ka0 = *(const s8v*)(K + (long)(l15) * HDIM + hi * 8);
  s8v ka1 = *(const s8v*)(K + (long)(l15) * HDIM + 32 + hi * 8);
  s8v ka2 = *(const s8v*)(K + (long)(16 + l15) * HDIM + hi * 8);
  s8v ka3 = *(const s8v*)(K + (long)(16 + l15) * HDIM + 32 + hi * 8);

  const int kv_end = q0 + 16;
  for (int kv0 = 0; kv0 < kv_end; kv0 += 32) {
    // QK^T swapped: D[kv][q], col q = l15, row kv = hi*4+r
    f4v s0 = __builtin_amdgcn_mfma_f32_16x16x32_bf16(ka0, qb0, zero, 0, 0, 0);
    s0     = __builtin_amdgcn_mfma_f32_16x16x32_bf16(ka1, qb1, s0,   0, 0, 0);
    f4v s1 = __builtin_amdgcn_mfma_f32_16x16x32_bf16(ka2, qb0, zero, 0, 0, 0);
    s1     = __builtin_amdgcn_mfma_f32_16x16x32_bf16(ka3, qb1, s1,   0, 0, 0);

    // prefetch next K tile (reads past kv_end stay inside workspace — unused)
    {
      const unsigned short* Kn = K + (long)(kv0 + 32) * HDIM;
      ka0 = *(const s8v*)(Kn + (long)(l15) * HDIM + hi * 8);
      ka1 = *(const s8v*)(Kn + (long)(l15) * HDIM + 32 + hi * 8);
      ka2 = *(const s8v*)(Kn + (long)(16 + l15) * HDIM + hi * 8);
      ka3 = *(const s8v*)(Kn + (long)(16 + l15) * HDIM + 32 + hi * 8);
    }
    // V tile (A-fragment: row d = l15, k = kv0 + hi*8+j) — issue early
    const s8v va0 = *(const s8v*)(Vt + (long)( 0 + l15) * SS + kv0 + hi * 8);
    const s8v va1 = *(const s8v*)(Vt + (long)(16 + l15) * SS + kv0 + hi * 8);
    const s8v va2 = *(const s8v*)(Vt + (long)(32 + l15) * SS + kv0 + hi * 8);
    const s8v va3 = *(const s8v*)(Vt + (long)(48 + l15) * SS + kv0 + hi * 8);

    float a0[4], a1[4];
#pragma unroll
    for (int r = 0; r < 4; ++r) { a0[r] = s0[r]; a1[r] = s1[r]; }
    if (kv0 + 31 > q0) {  // boundary tile: causal mask (kv <= q)
      const int qrel = q0 + l15 - kv0;
#pragma unroll
      for (int r = 0; r < 4; ++r) {
        a0[r] = (hi * 4 + r      <= qrel) ? a0[r] : -1e30f;
        a1[r] = (hi * 4 + r + 16 <= qrel) ? a1[r] : -1e30f;
      }
    }
    // row max over 32 kv: 7 fmax in-lane + 2 shfl_xor across hi-groups
    float mloc = fmaxf(fmaxf(fmaxf(a0[0], a0[1]), fmaxf(a0[2], a0[3])),
                       fmaxf(fmaxf(a1[0], a1[1]), fmaxf(a1[2], a1[3])));
    mloc = fmaxf(mloc, __shfl_xor(mloc, 16));
    mloc = fmaxf(mloc, __shfl_xor(mloc, 32));
    if (__any(mloc > m_run)) {   // defer-max: skip rescale when max unchanged
      const float mnew = fmaxf(m_run, mloc);
      const float corr = __expf(m_run - mnew);
      m_run = mnew;
      l_run *= corr;
#pragma unroll
      for (int t = 0; t < 4; ++t) accO[t] *= corr;
    }
    float p0[4], p1[4], sloc = 0.f;
#pragma unroll
    for (int r = 0; r < 4; ++r) {
      p0[r] = __expf(a0[r] - m_run);
      p1[r] = __expf(a1[r] - m_run);
      sloc += p0[r] + p1[r];
    }
    sloc += __shfl_xor(sloc, 16);
    sloc += __shfl_xor(sloc, 32);
    l_run += sloc;

    // redistribute P -> B-fragment b[j] = P[q=l15][kv0+hi*8+j]
    const unsigned u0 = pk2bf(p0[0], p0[1]);
    const unsigned u1 = pk2bf(p0[2], p0[3]);
    const unsigned u2 = pk2bf(p1[0], p1[1]);
    const unsigned u3 = pk2bf(p1[2], p1[3]);
    const unsigned xa0 = __shfl(u0, srcA), xa1 = __shfl(u1, srcA);
    const unsigned xa2 = __shfl(u2, srcA), xa3 = __shfl(u3, srcA);
    const unsigned xb0 = __shfl(u0, srcB), xb1 = __shfl(u1, srcB);
    const unsigned xb2 = __shfl(u2, srcB), xb3 = __shfl(u3, srcB);
    union { unsigned u[4]; s8v v; } pbu;
    pbu.u[0] = hih ? xa2 : xa0;
    pbu.u[1] = hih ? xa3 : xa1;
    pbu.u[2] = hih ? xb2 : xb0;
    pbu.u[3] = hih ? xb3 : xb1;
    const s8v pb = pbu.v;

    // PV: D[d][q] accumulate, 4 independent MFMAs
    accO[0] = __builtin_amdgcn_mfma_f32_16x16x32_bf16(va0, pb, accO[0], 0, 0, 0);
    accO[1] = __builtin_amdgcn_mfma_f32_16x16x32_bf16(va1, pb, accO[1], 0, 0, 0);
    accO[2] = __builtin_amdgcn_mfma_f32_16x16x32_bf16(va2, pb, accO[2], 0, 0, 0);
    accO[3] = __builtin_amdgcn_mfma_f32_16x16x32_bf16(va3, pb, accO[3], 0, 0, 0);
  }

  const float inv = 1.f / l_run;
  const int s = q0 + l15;
#pragma unroll
  for (int t = 0; t < 4; ++t) {
    ushort4 o;
    o.x = f2bf(accO[t][0] * inv);
    o.y = f2bf(accO[t][1] * inv);
    o.z = f2bf(accO[t][2] * inv);
    o.w = f2bf(accO[t][3] * inv);
    *(ushort4*)(obuf + (long)(b * SS + s) * HH + h * HDIM + t * 16 + hi * 4) = o;
  }
}

// ----------------- kernel 5: output projection -> fp32 d_out ----------------
__global__ __launch_bounds__(256) void out_gemm_kernel(
    const unsigned short* __restrict__ ob, const unsigned short* __restrict__ wot,
    float* __restrict__ out)
{
  const int lane = threadIdx.x & 63;
  const int wid  = threadIdx.x >> 6;
  const int l15 = lane & 15, hi = lane >> 4;
  const int m0 = blockIdx.x * 64 + wid * 16;
  const int n0 = blockIdx.y * 64;

  const f4v zero = {0.f, 0.f, 0.f, 0.f};
  f4v acc[4] = {zero, zero, zero, zero};

  for (int kk = 0; kk < 18; ++kk) {
    const int k0 = kk * 32 + hi * 8;
    s8v a = *(const s8v*)(ob + (long)(m0 + l15) * 576 + k0);
#pragma unroll
    for (int nb = 0; nb < 4; ++nb) {
      s8v b = *(const s8v*)(wot + (long)(n0 + nb * 16 + l15) * 576 + k0);
      acc[nb] = __builtin_amdgcn_mfma_f32_16x16x32_bf16(a, b, acc[nb], 0, 0, 0);
    }
  }
#pragma unroll
  for (int r = 0; r < 4; ++r) {
    const int row = m0 + hi * 4 + r;
#pragma unroll
    for (int nb = 0; nb < 4; ++nb) {
      out[(long)row * 576 + n0 + nb * 16 + l15] = acc[nb][r];
    }
  }
}

extern "C" void kernel_launch(void* const* d_in, const int* in_sizes, int n_in,
                              void* d_out, int out_size, void* d_ws, size_t ws_size,
                              hipStream_t stream) {
  const float* hs  = (const float*)d_in[0];
  const float* rot = (const float*)d_in[2];
  const float* wq  = (const float*)d_in[3];
  const float* wk  = (const float*)d_in[4];
  const float* wv  = (const float*)d_in[5];
  const float* wo  = (const float*)d_in[6];
  float* out = (float*)d_out;

  char* ws = (char*)d_ws;
  unsigned short* xb    = (unsigned short*)(ws + 0);          // 9,437,184
  unsigned short* wqkvt = (unsigned short*)(ws + 9437184);    // 1,105,920
  unsigned short* wot   = (unsigned short*)(ws + 10543104);   //   663,552
  unsigned short* qb    = (unsigned short*)(ws + 11206656);   // 9,437,184
  unsigned short* kb    = (unsigned short*)(ws + 20643840);   // 3,145,728
  unsigned short* vt    = (unsigned short*)(ws + 23789568);   // 3,145,728
  unsigned short* obuf  = (unsigned short*)(ws + 26935296);   // 9,437,184

  cast_x_kernel<<<4608, 256, 0, stream>>>(hs, xb);
  pack_w_kernel<<<3456, 256, 0, stream>>>(wq, wk, wv, wo, wqkvt, wot);
  qkv_gemm_kernel<<<dim3(128, 15), 256, 0, stream>>>(xb, wqkvt, rot, qb, kb, vt);
  flash_kernel<<<2304, 128, 0, stream>>>(qb, kb, vt, obuf);
  out_gemm_kernel<<<dim3(128, 9), 256, 0, stream>>>(obuf, wot, out);
}